// Round 3
// baseline (587.443 us; speedup 1.0000x reference)
//
#include <hip/hip_runtime.h>
#include <math.h>

#define NF 32

// ---- kernel 1: count out-degree (by src, for norm) and in-degree (by dst, for CSR)
__global__ void count_kernel(const int* __restrict__ src, const int* __restrict__ dst,
                             int* __restrict__ cnt_src, int* __restrict__ cnt_dst, int E) {
    int e = blockIdx.x * blockDim.x + threadIdx.x;
    if (e < E) {
        atomicAdd(&cnt_src[src[e]], 1);
        atomicAdd(&cnt_dst[dst[e]], 1);
    }
}

// ---- scan A: per-block inclusive scan of cnt_dst; also computes dis --------
__global__ void scanA_kernel(const int* __restrict__ cnt_dst, const int* __restrict__ cnt_src,
                             float* __restrict__ dis, int* __restrict__ incl,
                             int* __restrict__ bsum, int n) {
    __shared__ int s[256];
    int tid = threadIdx.x;
    int i = blockIdx.x * 256 + tid;
    s[tid] = (i < n) ? cnt_dst[i] : 0;
    if (i < n) {
        int d = cnt_src[i];
        dis[i] = (d > 0) ? rsqrtf((float)d) : 0.0f;
    }
    __syncthreads();
    for (int o = 1; o < 256; o <<= 1) {
        int t = (tid >= o) ? s[tid - o] : 0;
        __syncthreads();
        s[tid] += t;
        __syncthreads();
    }
    if (i < n) incl[i] = s[tid];
    if (tid == 255) bsum[blockIdx.x] = s[255];
}

__global__ void scanB_kernel(int* __restrict__ bsum, int nb) {
    __shared__ int s[512];
    int tid = threadIdx.x;
    s[tid] = (tid < nb) ? bsum[tid] : 0;
    __syncthreads();
    for (int o = 1; o < 512; o <<= 1) {
        int t = (tid >= o) ? s[tid - o] : 0;
        __syncthreads();
        s[tid] += t;
        __syncthreads();
    }
    if (tid < nb) bsum[tid] = (tid == 0) ? 0 : s[tid - 1];  // exclusive
}

__global__ void scanC_kernel(const int* __restrict__ incl, const int* __restrict__ cnt,
                             const int* __restrict__ bsum, int* __restrict__ cur, int n) {
    int i = blockIdx.x * 256 + threadIdx.x;
    if (i < n) cur[i] = incl[i] - cnt[i] + bsum[i >> 8];  // exclusive start
}

// ---- kernel 3: fill CSR buckets; pack (src<<3)|(dst&7) ---------------------
// after this kernel cur[n] holds END offsets
__global__ void fill_kernel(const int* __restrict__ src, const int* __restrict__ dst,
                            int* __restrict__ cur, int* __restrict__ bucket, int E) {
    int e = blockIdx.x * blockDim.x + threadIdx.x;
    if (e < E) {
        int s = src[e];
        int d = dst[e];
        int pos = atomicAdd(&cur[d], 1);
        bucket[pos] = (s << 3) | (d & 7);
    }
}

// ---- kernel 4: fused edge-parallel gather + gates + readout ----------------
// block = 256 threads = 8 nodes x 32 feature-lanes; bucket range is contiguous
__global__ __launch_bounds__(256) void gate_gather_kernel(
    const float* __restrict__ x, const int* __restrict__ bucket,
    const int* __restrict__ cur_end, const float* __restrict__ dis,
    const float* __restrict__ Wxz0, const float* __restrict__ Wxz1,
    const float* __restrict__ bxz,  const float* __restrict__ bhz,
    const float* __restrict__ Wxh0, const float* __restrict__ Wxh1,
    const float* __restrict__ bxh,  const float* __restrict__ bhh,
    const float* __restrict__ Wl,   const float* __restrict__ bl,
    float* __restrict__ out, int N)
{
    __shared__ float sWz0[NF * NF], sWz1[NF * NF], sWh0[NF * NF], sWh1[NF * NF];
    __shared__ float sbz[NF], sbh[NF], sWl[NF];
    __shared__ float sx[8][NF + 1], st[8][NF + 1];

    int t = threadIdx.x;
    int node0 = blockIdx.x * 8;

    for (int i = t; i < NF * NF; i += 256) {
        sWz0[i] = Wxz0[i];
        sWz1[i] = Wxz1[i];
        sWh0[i] = Wxh0[i];
        sWh1[i] = Wxh1[i];
    }
    if (t < NF) {
        sbz[t] = bxz[t] + bhz[t];
        sbh[t] = bxh[t] + bhh[t];
        sWl[t] = Wl[t];
    }

    int nl = t >> 5;          // node slot within block (0..7)
    int f  = t & 31;          // feature lane
    int node = node0 + nl;

    float dn = 0.0f;
    if (node < N) {
        sx[nl][f] = x[node * NF + f];
        dn = dis[node];
    }
    st[nl][f] = 0.0f;

    int e0 = (node0 == 0) ? 0 : cur_end[node0 - 1];
    int last = node0 + 7; if (last >= N) last = N - 1;
    int e1 = cur_end[last];
    __syncthreads();

    // edge-parallel gather: 8 edge-slots x 32 feature-lanes, unrolled x4 for MLP
    int M = e1 - e0;
    for (int base = 0; base < M; base += 32) {
        #pragma unroll
        for (int u = 0; u < 4; ++u) {
            int el = base + u * 8 + nl;
            int j = e0 + ((el < M) ? el : 0);
            int val = bucket[j];
            int s = val >> 3;
            int n = val & 7;
            float v = dis[s] * x[s * NF + f];
            if (el < M) atomicAdd(&st[n][f], v);
        }
    }
    __syncthreads();
    if (node >= N) return;

    float az0 = 0.0f, az1 = 0.0f, ah0 = 0.0f, ah1 = 0.0f;
    #pragma unroll
    for (int k = 0; k < NF; ++k) {
        float xv = sx[nl][k];
        float tv = st[nl][k];
        az0 += xv * sWz0[k * NF + f];
        az1 += tv * sWz1[k * NF + f];
        ah0 += xv * sWh0[k * NF + f];
        ah1 += tv * sWh1[k * NF + f];
    }
    float az = sbz[f] + az0 - dn * az1;   // -dis[dst] folded in here
    float ah = sbh[f] + ah0 - dn * ah1;

    float z  = 1.0f / (1.0f + expf(-az));
    float ht = tanhf(ah);
    float h  = (1.0f - z) * ht;
    float c  = fmaxf(h, 0.0f) * sWl[f];

    #pragma unroll
    for (int m = 16; m >= 1; m >>= 1) c += __shfl_xor(c, m, 64);

    if (f == 0) out[node] = c + bl[0];
}

extern "C" void kernel_launch(void* const* d_in, const int* in_sizes, int n_in,
                              void* d_out, int out_size, void* d_ws, size_t ws_size,
                              hipStream_t stream) {
    const float* x    = (const float*)d_in[0];
    const int*   edge = (const int*)d_in[1];   // [2, E]: src row then dst row
    const float* Wxz0 = (const float*)d_in[2];
    const float* Wxz1 = (const float*)d_in[3];
    const float* bxz  = (const float*)d_in[4];
    const float* bhz  = (const float*)d_in[7];
    const float* Wxh0 = (const float*)d_in[14];
    const float* Wxh1 = (const float*)d_in[15];
    const float* bxh  = (const float*)d_in[16];
    const float* bhh  = (const float*)d_in[19];
    const float* Wl   = (const float*)d_in[20];
    const float* bl   = (const float*)d_in[21];
    float* out = (float*)d_out;

    int N = in_sizes[0] / NF;
    int E = in_sizes[1] / 2;
    const int* src = edge;
    const int* dst = edge + E;

    // workspace (4B elems): cnt_src[N] | cnt_dst[N] | dis[N] | incl[N] | cur[N] | bsum[512] | bucket[E]
    int*   cnt_src = (int*)d_ws;
    int*   cnt_dst = cnt_src + N;
    float* dis     = (float*)(cnt_dst + N);
    int*   incl    = (int*)(dis + N);
    int*   cur     = incl + N;
    int*   bsum    = cur + N;
    int*   bucket  = bsum + 512;

    hipMemsetAsync(d_ws, 0, (size_t)2 * N * sizeof(int), stream);

    int eb = (E + 255) / 256;
    int nb = (N + 255) / 256;

    count_kernel<<<eb, 256, 0, stream>>>(src, dst, cnt_src, cnt_dst, E);
    scanA_kernel<<<nb, 256, 0, stream>>>(cnt_dst, cnt_src, dis, incl, bsum, N);
    scanB_kernel<<<1, 512, 0, stream>>>(bsum, nb);
    scanC_kernel<<<nb, 256, 0, stream>>>(incl, cnt_dst, bsum, cur, N);
    fill_kernel<<<eb, 256, 0, stream>>>(src, dst, cur, bucket, E);

    gate_gather_kernel<<<(N + 7) / 8, 256, 0, stream>>>(
        x, bucket, cur, dis,
        Wxz0, Wxz1, bxz, bhz, Wxh0, Wxh1, bxh, bhh, Wl, bl, out, N);
}

// Round 4
// 575.540 us; speedup vs baseline: 1.0207x; 1.0207x over previous
//
#include <hip/hip_runtime.h>
#include <math.h>

#define NF 32

// ---- kernel 1: count out-degree (by src, for norm) and in-degree (by dst, for CSR)
__global__ void count_kernel(const int* __restrict__ src, const int* __restrict__ dst,
                             int* __restrict__ cnt_src, int* __restrict__ cnt_dst, int E) {
    int e = blockIdx.x * blockDim.x + threadIdx.x;
    if (e < E) {
        atomicAdd(&cnt_src[src[e]], 1);
        atomicAdd(&cnt_dst[dst[e]], 1);
    }
}

// ---- scan A: per-block inclusive scan of cnt_dst; also computes dis --------
__global__ void scanA_kernel(const int* __restrict__ cnt_dst, const int* __restrict__ cnt_src,
                             float* __restrict__ dis, int* __restrict__ incl,
                             int* __restrict__ bsum, int n) {
    __shared__ int s[256];
    int tid = threadIdx.x;
    int i = blockIdx.x * 256 + tid;
    s[tid] = (i < n) ? cnt_dst[i] : 0;
    if (i < n) {
        int d = cnt_src[i];
        dis[i] = (d > 0) ? rsqrtf((float)d) : 0.0f;
    }
    __syncthreads();
    for (int o = 1; o < 256; o <<= 1) {
        int t = (tid >= o) ? s[tid - o] : 0;
        __syncthreads();
        s[tid] += t;
        __syncthreads();
    }
    if (i < n) incl[i] = s[tid];
    if (tid == 255) bsum[blockIdx.x] = s[255];
}

__global__ void scanB_kernel(int* __restrict__ bsum, int nb) {
    __shared__ int s[512];
    int tid = threadIdx.x;
    s[tid] = (tid < nb) ? bsum[tid] : 0;
    __syncthreads();
    for (int o = 1; o < 512; o <<= 1) {
        int t = (tid >= o) ? s[tid - o] : 0;
        __syncthreads();
        s[tid] += t;
        __syncthreads();
    }
    if (tid < nb) bsum[tid] = (tid == 0) ? 0 : s[tid - 1];  // exclusive
}

__global__ void scanC_kernel(const int* __restrict__ incl, const int* __restrict__ cnt,
                             const int* __restrict__ bsum, int* __restrict__ cur, int n) {
    int i = blockIdx.x * 256 + threadIdx.x;
    if (i < n) cur[i] = incl[i] - cnt[i] + bsum[i >> 8];  // exclusive start
}

// ---- kernel 3: fill CSR buckets; entry = { (src<<3)|(dst&7), dis[src] } ----
// after this kernel cur[n] holds END offsets
__global__ void fill_kernel(const int* __restrict__ src, const int* __restrict__ dst,
                            const float* __restrict__ dis,
                            int* __restrict__ cur, int2* __restrict__ bucket, int E) {
    int e = blockIdx.x * blockDim.x + threadIdx.x;
    if (e < E) {
        int s = src[e];
        int d = dst[e];
        float ds = dis[s];
        int pos = atomicAdd(&cur[d], 1);
        bucket[pos] = make_int2((s << 3) | (d & 7), __float_as_int(ds));
    }
}

// ---- kernel 4: fused gather (float4 lanes, LDS-staged bucket) + gates ------
// block = 256 threads, owns 8 consecutive nodes
#define CHUNK 256
__global__ __launch_bounds__(256) void gate_gather_kernel(
    const float* __restrict__ x, const int2* __restrict__ bucket,
    const int* __restrict__ cur_end, const float* __restrict__ dis,
    const float* __restrict__ Wxz0, const float* __restrict__ Wxz1,
    const float* __restrict__ bxz,  const float* __restrict__ bhz,
    const float* __restrict__ Wxh0, const float* __restrict__ Wxh1,
    const float* __restrict__ bxh,  const float* __restrict__ bhh,
    const float* __restrict__ Wl,   const float* __restrict__ bl,
    float* __restrict__ out, int N)
{
    __shared__ float sWz0[NF * NF], sWz1[NF * NF], sWh0[NF * NF], sWh1[NF * NF];
    __shared__ float sbz[NF], sbh[NF], sWl[NF];
    __shared__ float sx[8][NF + 1], st[8][NF + 1];
    __shared__ int2 sbkt[CHUNK];

    int t = threadIdx.x;
    int node0 = blockIdx.x * 8;

    for (int i = t; i < NF * NF; i += 256) {
        sWz0[i] = Wxz0[i];
        sWz1[i] = Wxz1[i];
        sWh0[i] = Wxh0[i];
        sWh1[i] = Wxh1[i];
    }
    if (t < NF) {
        sbz[t] = bxz[t] + bhz[t];
        sbh[t] = bxh[t] + bhh[t];
        sWl[t] = Wl[t];
    }

    int nl = t >> 5;          // node slot (0..7) for matmul phase
    int f  = t & 31;          // feature lane for matmul phase
    int node = node0 + nl;

    float dn = 0.0f;
    if (node < N) {
        sx[nl][f] = x[node * NF + f];
        dn = dis[node];
    }
    st[nl][f] = 0.0f;

    int e0 = (node0 == 0) ? 0 : cur_end[node0 - 1];
    int last = node0 + 7; if (last >= N) last = N - 1;
    int e1 = cur_end[last];
    int M = e1 - e0;

    int q  = t & 7;           // float4 quarter (0..7) for gather phase
    int es = t >> 3;          // edge slot (0..31) for gather phase

    for (int base = 0; base < M; base += CHUNK) {
        int cnt = M - base; if (cnt > CHUNK) cnt = CHUNK;
        __syncthreads();
        if (t < cnt) sbkt[t] = bucket[e0 + base + t];
        __syncthreads();

        for (int b2 = 0; b2 < cnt; b2 += 128) {
            float4 vv[4];
            int nn[4];
            #pragma unroll
            for (int u = 0; u < 4; ++u) {
                int el = b2 + u * 32 + es;
                int ec = (el < cnt) ? el : 0;
                int2 bv = sbkt[ec];
                int s = bv.x >> 3;
                nn[u] = (el < cnt) ? (bv.x & 7) : -1;
                float ds = __int_as_float(bv.y);
                float4 xv = *(const float4*)(x + (size_t)s * NF + q * 4);
                vv[u].x = ds * xv.x; vv[u].y = ds * xv.y;
                vv[u].z = ds * xv.z; vv[u].w = ds * xv.w;
            }
            #pragma unroll
            for (int u = 0; u < 4; ++u) {
                if (nn[u] >= 0) {
                    int c0 = q * 4;
                    atomicAdd(&st[nn[u]][c0 + 0], vv[u].x);
                    atomicAdd(&st[nn[u]][c0 + 1], vv[u].y);
                    atomicAdd(&st[nn[u]][c0 + 2], vv[u].z);
                    atomicAdd(&st[nn[u]][c0 + 3], vv[u].w);
                }
            }
        }
    }
    __syncthreads();
    if (node >= N) return;

    float az0 = 0.0f, az1 = 0.0f, ah0 = 0.0f, ah1 = 0.0f;
    #pragma unroll
    for (int k = 0; k < NF; ++k) {
        float xv = sx[nl][k];
        float tv = st[nl][k];
        az0 += xv * sWz0[k * NF + f];
        az1 += tv * sWz1[k * NF + f];
        ah0 += xv * sWh0[k * NF + f];
        ah1 += tv * sWh1[k * NF + f];
    }
    float az = sbz[f] + az0 - dn * az1;   // -dis[dst] folded in
    float ah = sbh[f] + ah0 - dn * ah1;

    float z  = 1.0f / (1.0f + expf(-az));
    float ht = tanhf(ah);
    float h  = (1.0f - z) * ht;
    float c  = fmaxf(h, 0.0f) * sWl[f];

    #pragma unroll
    for (int m = 16; m >= 1; m >>= 1) c += __shfl_xor(c, m, 64);

    if (f == 0) out[node] = c + bl[0];
}

extern "C" void kernel_launch(void* const* d_in, const int* in_sizes, int n_in,
                              void* d_out, int out_size, void* d_ws, size_t ws_size,
                              hipStream_t stream) {
    const float* x    = (const float*)d_in[0];
    const int*   edge = (const int*)d_in[1];   // [2, E]: src row then dst row
    const float* Wxz0 = (const float*)d_in[2];
    const float* Wxz1 = (const float*)d_in[3];
    const float* bxz  = (const float*)d_in[4];
    const float* bhz  = (const float*)d_in[7];
    const float* Wxh0 = (const float*)d_in[14];
    const float* Wxh1 = (const float*)d_in[15];
    const float* bxh  = (const float*)d_in[16];
    const float* bhh  = (const float*)d_in[19];
    const float* Wl   = (const float*)d_in[20];
    const float* bl   = (const float*)d_in[21];
    float* out = (float*)d_out;

    int N = in_sizes[0] / NF;
    int E = in_sizes[1] / 2;
    const int* src = edge;
    const int* dst = edge + E;

    // workspace (4B elems): cnt_src[N] | cnt_dst[N] | dis[N] | incl[N] | cur[N] | bsum[512] | pad | bucket2[E]*2
    int*   cnt_src = (int*)d_ws;
    int*   cnt_dst = cnt_src + N;
    float* dis     = (float*)(cnt_dst + N);
    int*   incl    = (int*)(dis + N);
    int*   cur     = incl + N;
    int*   bsum    = cur + N;
    int2*  bucket  = (int2*)(bsum + 512);  // 8B-aligned (offset from ws is 4N*5+2048 bytes; ws is 256B-aligned)

    hipMemsetAsync(d_ws, 0, (size_t)2 * N * sizeof(int), stream);

    int eb = (E + 255) / 256;
    int nb = (N + 255) / 256;

    count_kernel<<<eb, 256, 0, stream>>>(src, dst, cnt_src, cnt_dst, E);
    scanA_kernel<<<nb, 256, 0, stream>>>(cnt_dst, cnt_src, dis, incl, bsum, N);
    scanB_kernel<<<1, 512, 0, stream>>>(bsum, nb);
    scanC_kernel<<<nb, 256, 0, stream>>>(incl, cnt_dst, bsum, cur, N);
    fill_kernel<<<eb, 256, 0, stream>>>(src, dst, dis, cur, bucket, E);

    gate_gather_kernel<<<(N + 7) / 8, 256, 0, stream>>>(
        x, bucket, cur, dis,
        Wxz0, Wxz1, bxz, bhz, Wxh0, Wxh1, bxh, bhh, Wl, bl, out, N);
}

// Round 5
// 220.273 us; speedup vs baseline: 2.6669x; 2.6128x over previous
//
#include <hip/hip_runtime.h>
#include <hip/hip_fp16.h>
#include <math.h>

#define NF 32

__device__ __forceinline__ void atomic_pk_add_f16(unsigned int* addr, unsigned int val) {
    asm volatile("global_atomic_pk_add_f16 %0, %1, off" :: "v"(addr), "v"(val) : "memory");
}

// ---- kernel 1: out-degree by src (for norm) --------------------------------
__global__ void count_kernel(const int* __restrict__ src, int* __restrict__ cnt, int E) {
    int e = blockIdx.x * blockDim.x + threadIdx.x;
    if (e < E) atomicAdd(&cnt[src[e]], 1);
}

// ---- kernel 2: dis = deg>0 ? rsqrt(deg) : 0 ; xs = f16x2(dis * x) ----------
// thread per (node, feature-pair): t>>4 = node, t&15 = f2
__global__ void prescale_kernel(const float* __restrict__ x, const int* __restrict__ cnt,
                                float* __restrict__ dis, unsigned int* __restrict__ xs,
                                int N) {
    int t = blockIdx.x * blockDim.x + threadIdx.x;
    int n = t >> 4;
    int f2 = t & 15;
    if (n >= N) return;
    int d = cnt[n];
    float di = (d > 0) ? rsqrtf((float)d) : 0.0f;
    float2 xv = *(const float2*)(x + (size_t)n * NF + f2 * 2);
    unsigned short lo = __half_as_ushort(__float2half(di * xv.x));
    unsigned short hi = __half_as_ushort(__float2half(di * xv.y));
    xs[n * 16 + f2] = ((unsigned int)hi << 16) | lo;
    if (f2 == 0) dis[n] = di;
}

// ---- kernel 3: scatter acc[dst] += xs[src]  (packed f16 atomics) -----------
// thread per (edge, feature-pair)
__global__ void scatter_kernel(const int* __restrict__ src, const int* __restrict__ dst,
                               const unsigned int* __restrict__ xs,
                               unsigned int* __restrict__ acc, int E) {
    int t = blockIdx.x * blockDim.x + threadIdx.x;
    int e = t >> 4;
    int f2 = t & 15;
    if (e >= E) return;
    int s = src[e];
    int d = dst[e];
    unsigned int v = xs[s * 16 + f2];
    atomic_pk_add_f16(&acc[d * 16 + f2], v);
}

// ---- kernel 4: gates + readout ---------------------------------------------
// block = 256 threads = 8 nodes x 32 feature-lanes
__global__ __launch_bounds__(256) void gate_kernel(
    const float* __restrict__ x, const unsigned short* __restrict__ acc16,
    const float* __restrict__ dis,
    const float* __restrict__ Wxz0, const float* __restrict__ Wxz1,
    const float* __restrict__ bxz,  const float* __restrict__ bhz,
    const float* __restrict__ Wxh0, const float* __restrict__ Wxh1,
    const float* __restrict__ bxh,  const float* __restrict__ bhh,
    const float* __restrict__ Wl,   const float* __restrict__ bl,
    float* __restrict__ out, int N)
{
    __shared__ float sWz0[NF * NF], sWz1[NF * NF], sWh0[NF * NF], sWh1[NF * NF];
    __shared__ float sbz[NF], sbh[NF], sWl[NF];
    __shared__ float sx[8][NF + 1], st[8][NF + 1];

    int t = threadIdx.x;
    for (int i = t; i < NF * NF; i += 256) {
        sWz0[i] = Wxz0[i];
        sWz1[i] = Wxz1[i];
        sWh0[i] = Wxh0[i];
        sWh1[i] = Wxh1[i];
    }
    if (t < NF) {
        sbz[t] = bxz[t] + bhz[t];
        sbh[t] = bxh[t] + bhh[t];
        sWl[t] = Wl[t];
    }

    int nl = t >> 5;          // node slot (0..7)
    int f  = t & 31;          // feature lane
    int node = blockIdx.x * 8 + nl;

    if (node < N) {
        sx[nl][f] = x[(size_t)node * NF + f];
        float dn = dis[node];
        float av = __half2float(__ushort_as_half(acc16[(size_t)node * NF + f]));
        st[nl][f] = -dn * av;   // tx1 = -dis[dst] * sum(dis[src] * x[src])
    }
    __syncthreads();
    if (node >= N) return;

    float az = sbz[f];
    float ah = sbh[f];
    #pragma unroll
    for (int k = 0; k < NF; ++k) {
        float xv = sx[nl][k];
        float tv = st[nl][k];
        az += xv * sWz0[k * NF + f] + tv * sWz1[k * NF + f];
        ah += xv * sWh0[k * NF + f] + tv * sWh1[k * NF + f];
    }

    float z  = 1.0f / (1.0f + expf(-az));
    float ht = tanhf(ah);
    float h  = (1.0f - z) * ht;
    float c  = fmaxf(h, 0.0f) * sWl[f];

    #pragma unroll
    for (int m = 16; m >= 1; m >>= 1) c += __shfl_xor(c, m, 64);

    if (f == 0) out[node] = c + bl[0];
}

extern "C" void kernel_launch(void* const* d_in, const int* in_sizes, int n_in,
                              void* d_out, int out_size, void* d_ws, size_t ws_size,
                              hipStream_t stream) {
    const float* x    = (const float*)d_in[0];
    const int*   edge = (const int*)d_in[1];   // [2, E]: src row then dst row
    const float* Wxz0 = (const float*)d_in[2];
    const float* Wxz1 = (const float*)d_in[3];
    const float* bxz  = (const float*)d_in[4];
    const float* bhz  = (const float*)d_in[7];
    const float* Wxh0 = (const float*)d_in[14];
    const float* Wxh1 = (const float*)d_in[15];
    const float* bxh  = (const float*)d_in[16];
    const float* bhh  = (const float*)d_in[19];
    const float* Wl   = (const float*)d_in[20];
    const float* bl   = (const float*)d_in[21];
    float* out = (float*)d_out;

    int N = in_sizes[0] / NF;
    int E = in_sizes[1] / 2;
    const int* src = edge;
    const int* dst = edge + E;

    // workspace (4B elems), zeroed region first:
    // cnt[N] | acc[N*16] (half2) | dis[N] | xs[N*16] (half2)
    int*          cnt = (int*)d_ws;
    unsigned int* acc = (unsigned int*)(cnt + N);
    float*        dis = (float*)(acc + (size_t)N * 16);
    unsigned int* xs  = (unsigned int*)(dis + N);

    hipMemsetAsync(d_ws, 0, (size_t)(N + (size_t)N * 16) * sizeof(int), stream);

    count_kernel<<<(E + 255) / 256, 256, 0, stream>>>(src, cnt, E);

    int pt = N * 16;
    prescale_kernel<<<(pt + 255) / 256, 256, 0, stream>>>(x, cnt, dis, xs, N);

    long long stt = (long long)E * 16;
    scatter_kernel<<<(int)((stt + 255) / 256), 256, 0, stream>>>(src, dst, xs, acc, E);

    gate_kernel<<<(N + 7) / 8, 256, 0, stream>>>(
        x, (const unsigned short*)acc, dis,
        Wxz0, Wxz1, bxz, bhz, Wxh0, Wxh1, bxh, bhh, Wl, bl, out, N);
}